// Round 3
// baseline (291.120 us; speedup 1.0000x reference)
//
#include <hip/hip_runtime.h>

// Problem constants
#define BSEQ 64
#define LSEQ 512
#define CCH  1024
#define NT   7            // NUM_TAGS
#define NC   5            // real classes (labels are always 0..4)
#define NTOK (BSEQ*LSEQ)  // 32768
#define START_TAG 5
#define STOP_TAG  6
#define NEGV (-10000.0f)

// ---------------- DPP wave64 sum (result lands in lane 63) ----------------
template<int CTRL, int RMASK, int BMASK>
__device__ __forceinline__ float dpp_add(float x) {
    int y = __builtin_amdgcn_update_dpp(0, __float_as_int(x), CTRL, RMASK, BMASK, true);
    return x + __int_as_float(y);
}
__device__ __forceinline__ float wave_sum(float x) {
    x = dpp_add<0x111, 0xF, 0xF>(x);  // row_shr:1
    x = dpp_add<0x112, 0xF, 0xF>(x);  // row_shr:2
    x = dpp_add<0x114, 0xF, 0xF>(x);  // row_shr:4
    x = dpp_add<0x118, 0xF, 0xF>(x);  // row_shr:8  -> lane15 of each row16 has row sum
    x = dpp_add<0x142, 0xA, 0xF>(x);  // row_bcast:15 into rows 1,3
    x = dpp_add<0x143, 0xC, 0xF>(x);  // row_bcast:31 into rows 2,3 -> lane63 = total
    return x;
}

// 5-way log-sum-exp helper
__device__ __forceinline__ float lse5(const float v0, const float v1, const float v2,
                                      const float v3, const float v4) {
    float m = fmaxf(fmaxf(fmaxf(v0, v1), fmaxf(v2, v3)), v4);
    float s = __expf(v0 - m) + __expf(v1 - m) + __expf(v2 - m)
            + __expf(v3 - m) + __expf(v4 - m);
    return m + __logf(s);
}

// ---------------- Kernel 1: logits (X @ W^T + b), labels copy, score zero ----------------
// 1024 blocks (4 blocks/CU, 16 waves/CU) for HBM latency hiding; (256,4) caps
// VGPRs at 128 (live set ~110, no spill expected).
__global__ __launch_bounds__(256, 4)
void k_logits(const float* __restrict__ X, const float* __restrict__ W,
              const float* __restrict__ bvec, const int* __restrict__ lab,
              float* __restrict__ out)
{
    __shared__ float Wl[NT][CCH];   // 28 KB
    __shared__ float bl[NT];
    {
        const float4* W4  = (const float4*)W;
        float4*       Wl4 = (float4*)(&Wl[0][0]);
        for (int i = threadIdx.x; i < NT*CCH/4; i += 256) Wl4[i] = W4[i];
        if (threadIdx.x < NT) bl[threadIdx.x] = bvec[threadIdx.x];
    }
    __syncthreads();

    const int lane = threadIdx.x & 63;
    const int wid  = (blockIdx.x * 256 + threadIdx.x) >> 6;
    const int nw   = (gridDim.x * 256) >> 6;
    float* outP = out + 1 + NTOK;

    for (int base = wid * 4; base < NTOK; base += nw * 4) {
        // load 4 rows x 4 float4 per lane (coalesced 16B/lane)
        float4 xv[4][4];
        #pragma unroll
        for (int r = 0; r < 4; r++) {
            const float4* xr = (const float4*)(X + (size_t)(base + r) * CCH);
            #pragma unroll
            for (int k = 0; k < 4; k++) xv[k][r] = xr[k*64 + lane];
        }
        float acc[4][NT];
        #pragma unroll
        for (int r = 0; r < 4; r++)
            #pragma unroll
            for (int t = 0; t < NT; t++) acc[r][t] = 0.0f;

        #pragma unroll
        for (int k = 0; k < 4; k++) {
            const int cb = (k*64 + lane) * 4;
            #pragma unroll
            for (int t = 0; t < NT; t++) {
                const float4 wv = *(const float4*)(&Wl[t][cb]);   // unit-stride b128, conflict-free
                #pragma unroll
                for (int r = 0; r < 4; r++) {
                    acc[r][t] = fmaf(xv[k][r].x, wv.x,
                                fmaf(xv[k][r].y, wv.y,
                                fmaf(xv[k][r].z, wv.z,
                                fmaf(xv[k][r].w, wv.w, acc[r][t]))));
                }
            }
        }
        #pragma unroll
        for (int r = 0; r < 4; r++) {
            #pragma unroll
            for (int t = 0; t < NT; t++) {
                float s = wave_sum(acc[r][t]);
                if (lane == 63) outP[(size_t)(base + r) * NT + t] = s + bl[t];
            }
        }
    }

    // labels as float + zero the score slot
    for (int i = blockIdx.x * 256 + threadIdx.x; i < NTOK; i += gridDim.x * 256)
        out[1 + i] = (float)lab[i];
    if (blockIdx.x == 0 && threadIdx.x == 0) out[0] = 0.0f;
}

// ---------------- Kernel 2: CRF NLL, 5-class log-semiring chunked scan ----------------
// transitions[START,:]=NEG and [:,STOP]=NEG make the recurrence exactly 5x5 in
// fp32 (START enters only via step-0 injection u[k]=T[k,START]+e0[k]; STOP only
// at the final fold; all other START/STOP terms are exp(-10000-m) == 0.0f).
// Chunk 0 covers steps 1..7, chunks 1..63 cover 8 steps. 64 blocks x 320 thr
// (= 64 chunks x 5 basis). Tree-combine 64 5x5 matrices, fold u and T[STOP,:].
__global__ __launch_bounds__(320)
void k_crf(const float* __restrict__ dout_ro, const int* __restrict__ lab,
           const float* __restrict__ trans, float* __restrict__ score)
{
    __shared__ float E[LSEQ*NT];   // 3584 floats; reused as matrix buffer A after recurrence
    __shared__ float M2[32*25];    // ping-pong buffer B
    __shared__ float T[49];
    __shared__ float u_sh[NC];     // fv after step 0 (START injection)
    __shared__ float gred[5];

    const int b   = blockIdx.x;
    const int tid = threadIdx.x;
    const float* feats = dout_ro + 1 + NTOK + (size_t)b * (LSEQ*NT);

    for (int i = tid; i < LSEQ*NT; i += 320) E[i] = feats[i];
    if (tid < 49) T[tid] = trans[tid];
    __syncthreads();

    if (tid < NC) u_sh[tid] = T[tid*NT + START_TAG] + E[tid];   // e0[k] before E is overwritten

    // ---- gold score (parallel over tokens) ----
    float g = 0.0f;
    for (int l = tid; l < LSEQ; l += 320) {
        const int t  = lab[b*LSEQ + l];
        const int tp = (l == 0) ? START_TAG : lab[b*LSEQ + l - 1];
        g += E[l*NT + t] + T[t*NT + tp];
    }
    if (tid == 0) g += T[STOP_TAG*NT + lab[b*LSEQ + LSEQ - 1]];
    {
        float gs = wave_sum(g);
        if ((tid & 63) == 63) gred[tid >> 6] = gs;
    }

    // ---- chunk basis recurrences (5x5, all in registers) ----
    float TR[NC*NC];
    #pragma unroll
    for (int j = 0; j < NC; j++)
        #pragma unroll
        for (int k = 0; k < NC; k++) TR[j*NC + k] = T[j*NT + k];

    const int chunk = tid / NC;
    const int basis = tid - chunk * NC;
    float fv[NC];
    #pragma unroll
    for (int j = 0; j < NC; j++) fv[j] = (j == basis) ? 0.0f : NEGV;

    const int l0    = (chunk == 0) ? 1 : chunk * 8;
    const int steps = (chunk == 0) ? 7 : 8;
    for (int s = 0; s < steps; s++) {
        const int l = l0 + s;
        float fn[NC];
        #pragma unroll
        for (int j = 0; j < NC; j++) {
            fn[j] = lse5(fv[0] + TR[j*NC+0], fv[1] + TR[j*NC+1], fv[2] + TR[j*NC+2],
                         fv[3] + TR[j*NC+3], fv[4] + TR[j*NC+4]) + E[l*NT + j];
        }
        #pragma unroll
        for (int j = 0; j < NC; j++) fv[j] = fn[j];
    }
    __syncthreads();   // all E reads done; safe to overwrite with matrices
    #pragma unroll
    for (int j = 0; j < NC; j++) E[chunk*25 + basis*NC + j] = fv[j];

    // ---- tree combine: C[i][j] = lse_k(A[i][k] + B[k][j]), chronological L->R ----
    // (no LDS-pointer arrays: addrspacecast static-init is rejected on gfx950)
    int n = 64, cur = 0;
    while (n > 1) {
        __syncthreads();
        const float* in = (cur == 0) ? (const float*)E : (const float*)M2;
        float*       ob = (cur == 0) ? M2 : E;
        const int half = n >> 1;
        for (int e2 = tid; e2 < half*25; e2 += 320) {
            const int p = e2 / 25, r = e2 - p*25;
            const int i = r / NC, j = r - (r/NC)*NC;
            const float* A  = in + (2*p)*25 + i*NC;
            const float* Bm = in + (2*p + 1)*25 + j;
            ob[p*25 + r] = lse5(A[0] + Bm[0], A[1] + Bm[NC], A[2] + Bm[2*NC],
                                A[3] + Bm[3*NC], A[4] + Bm[4*NC]);
        }
        cur ^= 1; n = half;
    }
    __syncthreads();

    if (tid == 0) {
        float gg = gred[0] + gred[1] + gred[2] + gred[3] + gred[4];
        const float* M = (cur == 0) ? (const float*)E : (const float*)M2;  // final 5x5
        float v[NC];
        #pragma unroll
        for (int j = 0; j < NC; j++)
            v[j] = lse5(u_sh[0] + M[0*NC+j], u_sh[1] + M[1*NC+j], u_sh[2] + M[2*NC+j],
                        u_sh[3] + M[3*NC+j], u_sh[4] + M[4*NC+j]);
        float fwd = lse5(v[0] + T[STOP_TAG*NT+0], v[1] + T[STOP_TAG*NT+1],
                         v[2] + T[STOP_TAG*NT+2], v[3] + T[STOP_TAG*NT+3],
                         v[4] + T[STOP_TAG*NT+4]);
        atomicAdd(score, fwd - gg);
    }
}

extern "C" void kernel_launch(void* const* d_in, const int* in_sizes, int n_in,
                              void* d_out, int out_size, void* d_ws, size_t ws_size,
                              hipStream_t stream) {
    const float* X     = (const float*)d_in[0];   // fuse_embeddings [32768,1024]
    const int*   lab   = (const int*)  d_in[1];   // label_class [32768]
    const float* W     = (const float*)d_in[2];   // [7,1024]
    const float* bvec  = (const float*)d_in[3];   // [7]
    const float* trans = (const float*)d_in[4];   // [7,7]
    float* out = (float*)d_out;

    k_logits<<<1024, 256, 0, stream>>>(X, W, bvec, lab, out);
    k_crf<<<BSEQ, 320, 0, stream>>>(out, lab, trans, out);
}

// Round 4
// 219.293 us; speedup vs baseline: 1.3275x; 1.3275x over previous
//
#include <hip/hip_runtime.h>

// Problem constants
#define BSEQ 64
#define LSEQ 512
#define CCH  1024
#define NT   7            // NUM_TAGS
#define NC   5            // real classes (labels are always 0..4)
#define NTOK (BSEQ*LSEQ)  // 32768
#define START_TAG 5
#define STOP_TAG  6
#define NEGV (-10000.0f)

// ---------------- DPP wave64 sum (result lands in lane 63) ----------------
template<int CTRL, int RMASK, int BMASK>
__device__ __forceinline__ float dpp_add(float x) {
    int y = __builtin_amdgcn_update_dpp(0, __float_as_int(x), CTRL, RMASK, BMASK, true);
    return x + __int_as_float(y);
}
__device__ __forceinline__ float wave_sum(float x) {
    x = dpp_add<0x111, 0xF, 0xF>(x);  // row_shr:1
    x = dpp_add<0x112, 0xF, 0xF>(x);  // row_shr:2
    x = dpp_add<0x114, 0xF, 0xF>(x);  // row_shr:4
    x = dpp_add<0x118, 0xF, 0xF>(x);  // row_shr:8  -> lane15 of each row16 has row sum
    x = dpp_add<0x142, 0xA, 0xF>(x);  // row_bcast:15 into rows 1,3
    x = dpp_add<0x143, 0xC, 0xF>(x);  // row_bcast:31 into rows 2,3 -> lane63 = total
    return x;
}

// 5-way log-sum-exp helper
__device__ __forceinline__ float lse5(const float v0, const float v1, const float v2,
                                      const float v3, const float v4) {
    float m = fmaxf(fmaxf(fmaxf(v0, v1), fmaxf(v2, v3)), v4);
    float s = __expf(v0 - m) + __expf(v1 - m) + __expf(v2 - m)
            + __expf(v3 - m) + __expf(v4 - m);
    return m + __logf(s);
}

// ---------------- Kernel 1: logits (X @ W^T + b), labels copy, score zero ----------------
// NOTE: no min-waves arg in __launch_bounds__ — R3 showed (256,4) clamps the
// allocator to 64 VGPRs (live set ~110) -> 88 MB of scratch spill writes and
// 2.2x FETCH over-read. Plain (256) lets the compiler take ~110-128 VGPRs
// (16 waves/CU), no spills. BW-bound: VALU ~4 us << HBM ~21 us floor.
__global__ __launch_bounds__(256)
void k_logits(const float* __restrict__ X, const float* __restrict__ W,
              const float* __restrict__ bvec, const int* __restrict__ lab,
              float* __restrict__ out)
{
    __shared__ float Wl[NT][CCH];   // 28 KB
    __shared__ float bl[NT];
    {
        const float4* W4  = (const float4*)W;
        float4*       Wl4 = (float4*)(&Wl[0][0]);
        for (int i = threadIdx.x; i < NT*CCH/4; i += 256) Wl4[i] = W4[i];
        if (threadIdx.x < NT) bl[threadIdx.x] = bvec[threadIdx.x];
    }
    __syncthreads();

    const int lane = threadIdx.x & 63;
    const int wid  = (blockIdx.x * 256 + threadIdx.x) >> 6;
    const int nw   = (gridDim.x * 256) >> 6;
    float* outP = out + 1 + NTOK;

    for (int base = wid * 4; base < NTOK; base += nw * 4) {
        // load 4 rows x 4 float4 per lane (coalesced 16B/lane)
        float4 xv[4][4];
        #pragma unroll
        for (int r = 0; r < 4; r++) {
            const float4* xr = (const float4*)(X + (size_t)(base + r) * CCH);
            #pragma unroll
            for (int k = 0; k < 4; k++) xv[k][r] = xr[k*64 + lane];
        }
        float acc[4][NT];
        #pragma unroll
        for (int r = 0; r < 4; r++)
            #pragma unroll
            for (int t = 0; t < NT; t++) acc[r][t] = 0.0f;

        #pragma unroll
        for (int k = 0; k < 4; k++) {
            const int cb = (k*64 + lane) * 4;
            #pragma unroll
            for (int t = 0; t < NT; t++) {
                const float4 wv = *(const float4*)(&Wl[t][cb]);   // unit-stride b128, conflict-free
                #pragma unroll
                for (int r = 0; r < 4; r++) {
                    acc[r][t] = fmaf(xv[k][r].x, wv.x,
                                fmaf(xv[k][r].y, wv.y,
                                fmaf(xv[k][r].z, wv.z,
                                fmaf(xv[k][r].w, wv.w, acc[r][t]))));
                }
            }
        }
        #pragma unroll
        for (int r = 0; r < 4; r++) {
            #pragma unroll
            for (int t = 0; t < NT; t++) {
                float s = wave_sum(acc[r][t]);
                if (lane == 63) outP[(size_t)(base + r) * NT + t] = s + bl[t];
            }
        }
    }

    // labels as float + zero the score slot
    for (int i = blockIdx.x * 256 + threadIdx.x; i < NTOK; i += gridDim.x * 256)
        out[1 + i] = (float)lab[i];
    if (blockIdx.x == 0 && threadIdx.x == 0) out[0] = 0.0f;
}

// ---------------- Kernel 2: CRF NLL, 5-class log-semiring chunked scan ----------------
// transitions[START,:]=NEG and [:,STOP]=NEG make the recurrence exactly 5x5 in
// fp32 (START enters only via step-0 injection u[k]=T[k,START]+e0[k]; STOP only
// at the final fold; all other START/STOP terms are exp(-10000-m) == 0.0f).
// Chunk 0 covers steps 1..7, chunks 1..63 cover 8 steps. 64 blocks x 320 thr
// (= 64 chunks x 5 basis). Tree-combine 64 5x5 matrices, fold u and T[STOP,:].
__global__ __launch_bounds__(320)
void k_crf(const float* __restrict__ dout_ro, const int* __restrict__ lab,
           const float* __restrict__ trans, float* __restrict__ score)
{
    __shared__ float E[LSEQ*NT];   // 3584 floats; reused as matrix buffer A after recurrence
    __shared__ float M2[32*25];    // ping-pong buffer B
    __shared__ float T[49];
    __shared__ float u_sh[NC];     // fv after step 0 (START injection)
    __shared__ float gred[5];

    const int b   = blockIdx.x;
    const int tid = threadIdx.x;
    const float* feats = dout_ro + 1 + NTOK + (size_t)b * (LSEQ*NT);

    for (int i = tid; i < LSEQ*NT; i += 320) E[i] = feats[i];
    if (tid < 49) T[tid] = trans[tid];
    __syncthreads();

    if (tid < NC) u_sh[tid] = T[tid*NT + START_TAG] + E[tid];   // e0[k] before E is overwritten

    // ---- gold score (parallel over tokens) ----
    float g = 0.0f;
    for (int l = tid; l < LSEQ; l += 320) {
        const int t  = lab[b*LSEQ + l];
        const int tp = (l == 0) ? START_TAG : lab[b*LSEQ + l - 1];
        g += E[l*NT + t] + T[t*NT + tp];
    }
    if (tid == 0) g += T[STOP_TAG*NT + lab[b*LSEQ + LSEQ - 1]];
    {
        float gs = wave_sum(g);
        if ((tid & 63) == 63) gred[tid >> 6] = gs;
    }

    // ---- chunk basis recurrences (5x5, all in registers) ----
    float TR[NC*NC];
    #pragma unroll
    for (int j = 0; j < NC; j++)
        #pragma unroll
        for (int k = 0; k < NC; k++) TR[j*NC + k] = T[j*NT + k];

    const int chunk = tid / NC;
    const int basis = tid - chunk * NC;
    float fv[NC];
    #pragma unroll
    for (int j = 0; j < NC; j++) fv[j] = (j == basis) ? 0.0f : NEGV;

    const int l0    = (chunk == 0) ? 1 : chunk * 8;
    const int steps = (chunk == 0) ? 7 : 8;
    for (int s = 0; s < steps; s++) {
        const int l = l0 + s;
        float fn[NC];
        #pragma unroll
        for (int j = 0; j < NC; j++) {
            fn[j] = lse5(fv[0] + TR[j*NC+0], fv[1] + TR[j*NC+1], fv[2] + TR[j*NC+2],
                         fv[3] + TR[j*NC+3], fv[4] + TR[j*NC+4]) + E[l*NT + j];
        }
        #pragma unroll
        for (int j = 0; j < NC; j++) fv[j] = fn[j];
    }
    __syncthreads();   // all E reads done; safe to overwrite with matrices
    #pragma unroll
    for (int j = 0; j < NC; j++) E[chunk*25 + basis*NC + j] = fv[j];

    // ---- tree combine: C[i][j] = lse_k(A[i][k] + B[k][j]), chronological L->R ----
    // (no LDS-pointer arrays: addrspacecast static-init is rejected on gfx950)
    int n = 64, cur = 0;
    while (n > 1) {
        __syncthreads();
        const float* in = (cur == 0) ? (const float*)E : (const float*)M2;
        float*       ob = (cur == 0) ? M2 : E;
        const int half = n >> 1;
        for (int e2 = tid; e2 < half*25; e2 += 320) {
            const int p = e2 / 25, r = e2 - p*25;
            const int i = r / NC, j = r - (r/NC)*NC;
            const float* A  = in + (2*p)*25 + i*NC;
            const float* Bm = in + (2*p + 1)*25 + j;
            ob[p*25 + r] = lse5(A[0] + Bm[0], A[1] + Bm[NC], A[2] + Bm[2*NC],
                                A[3] + Bm[3*NC], A[4] + Bm[4*NC]);
        }
        cur ^= 1; n = half;
    }
    __syncthreads();

    if (tid == 0) {
        float gg = gred[0] + gred[1] + gred[2] + gred[3] + gred[4];
        const float* M = (cur == 0) ? (const float*)E : (const float*)M2;  // final 5x5
        float v[NC];
        #pragma unroll
        for (int j = 0; j < NC; j++)
            v[j] = lse5(u_sh[0] + M[0*NC+j], u_sh[1] + M[1*NC+j], u_sh[2] + M[2*NC+j],
                        u_sh[3] + M[3*NC+j], u_sh[4] + M[4*NC+j]);
        float fwd = lse5(v[0] + T[STOP_TAG*NT+0], v[1] + T[STOP_TAG*NT+1],
                         v[2] + T[STOP_TAG*NT+2], v[3] + T[STOP_TAG*NT+3],
                         v[4] + T[STOP_TAG*NT+4]);
        atomicAdd(score, fwd - gg);
    }
}

extern "C" void kernel_launch(void* const* d_in, const int* in_sizes, int n_in,
                              void* d_out, int out_size, void* d_ws, size_t ws_size,
                              hipStream_t stream) {
    const float* X     = (const float*)d_in[0];   // fuse_embeddings [32768,1024]
    const int*   lab   = (const int*)  d_in[1];   // label_class [32768]
    const float* W     = (const float*)d_in[2];   // [7,1024]
    const float* bvec  = (const float*)d_in[3];   // [7]
    const float* trans = (const float*)d_in[4];   // [7,7]
    float* out = (float*)d_out;

    k_logits<<<1024, 256, 0, stream>>>(X, W, bvec, lab, out);
    k_crf<<<BSEQ, 320, 0, stream>>>(out, lab, trans, out);
}

// Round 6
// 209.686 us; speedup vs baseline: 1.3884x; 1.0458x over previous
//
#include <hip/hip_runtime.h>

// Problem constants
#define BSEQ 64
#define LSEQ 512
#define CCH  1024
#define NT   7            // NUM_TAGS
#define NC   5            // real classes (labels are always 0..4)
#define NTOK (BSEQ*LSEQ)  // 32768
#define START_TAG 5
#define STOP_TAG  6
#define NEGV (-10000.0f)
#define GRID_LOGITS 1024  // k_logits assumes exactly this grid (4 iters/wave)

// native clang vector: __builtin_nontemporal_load rejects HIP_vector_type
// (struct); ext_vector_type(4) float is accepted and layout-identical.
typedef float vfloat4 __attribute__((ext_vector_type(4)));

// ---------------- DPP wave64 sum (result lands in lane 63) ----------------
template<int CTRL, int RMASK, int BMASK>
__device__ __forceinline__ float dpp_add(float x) {
    int y = __builtin_amdgcn_update_dpp(0, __float_as_int(x), CTRL, RMASK, BMASK, true);
    return x + __int_as_float(y);
}
__device__ __forceinline__ float wave_sum(float x) {
    x = dpp_add<0x111, 0xF, 0xF>(x);  // row_shr:1
    x = dpp_add<0x112, 0xF, 0xF>(x);  // row_shr:2
    x = dpp_add<0x114, 0xF, 0xF>(x);  // row_shr:4
    x = dpp_add<0x118, 0xF, 0xF>(x);  // row_shr:8  -> lane15 of each row16 has row sum
    x = dpp_add<0x142, 0xA, 0xF>(x);  // row_bcast:15 into rows 1,3
    x = dpp_add<0x143, 0xC, 0xF>(x);  // row_bcast:31 into rows 2,3 -> lane63 = total
    return x;
}

// 5-way log-sum-exp helper
__device__ __forceinline__ float lse5(const float v0, const float v1, const float v2,
                                      const float v3, const float v4) {
    float m = fmaxf(fmaxf(fmaxf(v0, v1), fmaxf(v2, v3)), v4);
    float s = __expf(v0 - m) + __expf(v1 - m) + __expf(v2 - m)
            + __expf(v3 - m) + __expf(v4 - m);
    return m + __logf(s);
}

// ---------------- Kernel 1: logits (X @ W^T + b), labels copy, score zero ----------------
// R4 evidence: 68 us @ 2 TB/s, occupancy-insensitive, VALUBusy ~8% -> waves
// stall together in a load->full-drain->compute cadence (no loads in flight
// during compute). Fix: 2 rows/iter, 4 iters/wave, fully-unrolled ping-pong
// register prefetch (next iter's 8 float4 issued before current compute, so
// the wait is a partial vmcnt, ~8KB always in flight per wave) + nontemporal
// X loads (streamed once, don't retain in L2).
// NOTE: plain __launch_bounds__(256) — R3 showed (256,4) clamps to 64 VGPR
// and spills 88 MB. Live set here ~110 VGPR.
__global__ __launch_bounds__(256)
void k_logits(const float* __restrict__ X, const float* __restrict__ W,
              const float* __restrict__ bvec, const int* __restrict__ lab,
              float* __restrict__ out)
{
    __shared__ float Wl[NT][CCH];   // 28 KB
    __shared__ float bl[NT];
    {
        const vfloat4* W4  = (const vfloat4*)W;
        vfloat4*       Wl4 = (vfloat4*)(&Wl[0][0]);
        for (int i = threadIdx.x; i < NT*CCH/4; i += 256) Wl4[i] = W4[i];
        if (threadIdx.x < NT) bl[threadIdx.x] = bvec[threadIdx.x];
    }
    __syncthreads();

    const int lane = threadIdx.x & 63;
    const int wid  = (blockIdx.x * 256 + threadIdx.x) >> 6;
    const int nw   = (GRID_LOGITS * 256) >> 6;      // 4096 waves
    float* outP = out + 1 + NTOK;

    vfloat4 xv[2][2][4];   // [buf][row][k]  -- static indices after full unroll

    // prologue: load iteration 0 into buf 0
    {
        const size_t r0 = (size_t)wid * 2;
        const vfloat4* x0 = (const vfloat4*)(X + r0 * CCH);
        const vfloat4* x1 = (const vfloat4*)(X + (r0 + 1) * CCH);
        #pragma unroll
        for (int k = 0; k < 4; k++) {
            xv[0][0][k] = __builtin_nontemporal_load(&x0[k*64 + lane]);
            xv[0][1][k] = __builtin_nontemporal_load(&x1[k*64 + lane]);
        }
    }

    #pragma unroll
    for (int it = 0; it < 4; ++it) {
        const int buf = it & 1;
        // prefetch next iteration before touching current buffer
        if (it < 3) {
            const size_t rn = (size_t)(wid + (it + 1) * nw) * 2;
            const vfloat4* x0 = (const vfloat4*)(X + rn * CCH);
            const vfloat4* x1 = (const vfloat4*)(X + (rn + 1) * CCH);
            #pragma unroll
            for (int k = 0; k < 4; k++) {
                xv[buf ^ 1][0][k] = __builtin_nontemporal_load(&x0[k*64 + lane]);
                xv[buf ^ 1][1][k] = __builtin_nontemporal_load(&x1[k*64 + lane]);
            }
        }

        float acc[2][NT];
        #pragma unroll
        for (int r = 0; r < 2; r++)
            #pragma unroll
            for (int t = 0; t < NT; t++) acc[r][t] = 0.0f;

        #pragma unroll
        for (int k = 0; k < 4; k++) {
            const int cb = (k*64 + lane) * 4;
            #pragma unroll
            for (int t = 0; t < NT; t++) {
                const vfloat4 wv = *(const vfloat4*)(&Wl[t][cb]);   // unit-stride b128, conflict-free
                #pragma unroll
                for (int r = 0; r < 2; r++) {
                    acc[r][t] = fmaf(xv[buf][r][k].x, wv.x,
                                fmaf(xv[buf][r][k].y, wv.y,
                                fmaf(xv[buf][r][k].z, wv.z,
                                fmaf(xv[buf][r][k].w, wv.w, acc[r][t]))));
                }
            }
        }

        const size_t base = (size_t)(wid + it * nw) * 2;
        #pragma unroll
        for (int r = 0; r < 2; r++) {
            #pragma unroll
            for (int t = 0; t < NT; t++) {
                float s = wave_sum(acc[r][t]);
                if (lane == 63) outP[(base + r) * NT + t] = s + bl[t];
            }
        }
    }

    // labels as float + zero the score slot
    for (int i = blockIdx.x * 256 + threadIdx.x; i < NTOK; i += GRID_LOGITS * 256)
        out[1 + i] = (float)lab[i];
    if (blockIdx.x == 0 && threadIdx.x == 0) out[0] = 0.0f;
}

// ---------------- Kernel 2: CRF NLL, 5-class log-semiring chunked scan ----------------
// transitions[START,:]=NEG and [:,STOP]=NEG make the recurrence exactly 5x5 in
// fp32 (START enters only via step-0 injection u[k]=T[k,START]+e0[k]; STOP only
// at the final fold; all other START/STOP terms are exp(-10000-m) == 0.0f).
// Chunk 0 covers steps 1..7, chunks 1..63 cover 8 steps. 64 blocks x 320 thr
// (= 64 chunks x 5 basis). Tree-combine 64 5x5 matrices, fold u and T[STOP,:].
__global__ __launch_bounds__(320)
void k_crf(const float* __restrict__ dout_ro, const int* __restrict__ lab,
           const float* __restrict__ trans, float* __restrict__ score)
{
    __shared__ float E[LSEQ*NT];   // 3584 floats; reused as matrix buffer A after recurrence
    __shared__ float M2[32*25];    // ping-pong buffer B
    __shared__ float T[49];
    __shared__ float u_sh[NC];     // fv after step 0 (START injection)
    __shared__ float gred[5];

    const int b   = blockIdx.x;
    const int tid = threadIdx.x;
    const float* feats = dout_ro + 1 + NTOK + (size_t)b * (LSEQ*NT);

    for (int i = tid; i < LSEQ*NT; i += 320) E[i] = feats[i];
    if (tid < 49) T[tid] = trans[tid];
    __syncthreads();

    if (tid < NC) u_sh[tid] = T[tid*NT + START_TAG] + E[tid];   // e0[k] before E is overwritten

    // ---- gold score (parallel over tokens) ----
    float g = 0.0f;
    for (int l = tid; l < LSEQ; l += 320) {
        const int t  = lab[b*LSEQ + l];
        const int tp = (l == 0) ? START_TAG : lab[b*LSEQ + l - 1];
        g += E[l*NT + t] + T[t*NT + tp];
    }
    if (tid == 0) g += T[STOP_TAG*NT + lab[b*LSEQ + LSEQ - 1]];
    {
        float gs = wave_sum(g);
        if ((tid & 63) == 63) gred[tid >> 6] = gs;
    }

    // ---- chunk basis recurrences (5x5, all in registers) ----
    float TR[NC*NC];
    #pragma unroll
    for (int j = 0; j < NC; j++)
        #pragma unroll
        for (int k = 0; k < NC; k++) TR[j*NC + k] = T[j*NT + k];

    const int chunk = tid / NC;
    const int basis = tid - chunk * NC;
    float fv[NC];
    #pragma unroll
    for (int j = 0; j < NC; j++) fv[j] = (j == basis) ? 0.0f : NEGV;

    const int l0    = (chunk == 0) ? 1 : chunk * 8;
    const int steps = (chunk == 0) ? 7 : 8;
    for (int s = 0; s < steps; s++) {
        const int l = l0 + s;
        float fn[NC];
        #pragma unroll
        for (int j = 0; j < NC; j++) {
            fn[j] = lse5(fv[0] + TR[j*NC+0], fv[1] + TR[j*NC+1], fv[2] + TR[j*NC+2],
                         fv[3] + TR[j*NC+3], fv[4] + TR[j*NC+4]) + E[l*NT + j];
        }
        #pragma unroll
        for (int j = 0; j < NC; j++) fv[j] = fn[j];
    }
    __syncthreads();   // all E reads done; safe to overwrite with matrices
    #pragma unroll
    for (int j = 0; j < NC; j++) E[chunk*25 + basis*NC + j] = fv[j];

    // ---- tree combine: C[i][j] = lse_k(A[i][k] + B[k][j]), chronological L->R ----
    // (no LDS-pointer arrays: addrspacecast static-init is rejected on gfx950)
    int n = 64, cur = 0;
    while (n > 1) {
        __syncthreads();
        const float* in = (cur == 0) ? (const float*)E : (const float*)M2;
        float*       ob = (cur == 0) ? M2 : E;
        const int half = n >> 1;
        for (int e2 = tid; e2 < half*25; e2 += 320) {
            const int p = e2 / 25, r = e2 - p*25;
            const int i = r / NC, j = r - (r/NC)*NC;
            const float* A  = in + (2*p)*25 + i*NC;
            const float* Bm = in + (2*p + 1)*25 + j;
            ob[p*25 + r] = lse5(A[0] + Bm[0], A[1] + Bm[NC], A[2] + Bm[2*NC],
                                A[3] + Bm[3*NC], A[4] + Bm[4*NC]);
        }
        cur ^= 1; n = half;
    }
    __syncthreads();

    if (tid == 0) {
        float gg = gred[0] + gred[1] + gred[2] + gred[3] + gred[4];
        const float* M = (cur == 0) ? (const float*)E : (const float*)M2;  // final 5x5
        float v[NC];
        #pragma unroll
        for (int j = 0; j < NC; j++)
            v[j] = lse5(u_sh[0] + M[0*NC+j], u_sh[1] + M[1*NC+j], u_sh[2] + M[2*NC+j],
                        u_sh[3] + M[3*NC+j], u_sh[4] + M[4*NC+j]);
        float fwd = lse5(v[0] + T[STOP_TAG*NT+0], v[1] + T[STOP_TAG*NT+1],
                         v[2] + T[STOP_TAG*NT+2], v[3] + T[STOP_TAG*NT+3],
                         v[4] + T[STOP_TAG*NT+4]);
        atomicAdd(score, fwd - gg);
    }
}

extern "C" void kernel_launch(void* const* d_in, const int* in_sizes, int n_in,
                              void* d_out, int out_size, void* d_ws, size_t ws_size,
                              hipStream_t stream) {
    const float* X     = (const float*)d_in[0];   // fuse_embeddings [32768,1024]
    const int*   lab   = (const int*)  d_in[1];   // label_class [32768]
    const float* W     = (const float*)d_in[2];   // [7,1024]
    const float* bvec  = (const float*)d_in[3];   // [7]
    const float* trans = (const float*)d_in[4];   // [7,7]
    float* out = (float*)d_out;

    k_logits<<<GRID_LOGITS, 256, 0, stream>>>(X, W, bvec, lab, out);
    k_crf<<<BSEQ, 320, 0, stream>>>(out, lab, trans, out);
}